// Round 5
// baseline (1035.014 us; speedup 1.0000x reference)
//
#include <hip/hip_runtime.h>

#define LROW    2904
#define PERIOD  24
#define CYC     121          // LROW / PERIOD (odd -> median = 0-indexed rank 60)
#define NT      256
#define NF      207
#define NB      64
#define NROWS   13248        // NB * NF
#define NPAIR   (NROWS / 2)  // 6624 = 8 * 828
#define PCHUNK  (NPAIR / 8)
#define LTILE   24
#define NLT     (LROW / LTILE)   // 121
#define K2GRID  (NB * NLT)       // 7744 = 8 * 968
#define K2CHUNK (K2GRID / 8)
#define HISTW   49           // 32 bins x 48 cols, stride 49 (odd -> scan conflict-free)

__device__ __forceinline__ int clampi(int i) {
    return i < 0 ? 0 : (i >= LROW ? LROW - 1 : i);
}
__device__ __forceinline__ unsigned sortable(float x) {
    unsigned u = __float_as_uint(x);
    return u ^ ((unsigned)((int)u >> 31) | 0x80000000u);
}
__device__ __forceinline__ float unsortable(unsigned k) {
    unsigned u = ((int)k >= 0) ? ~k : (k ^ 0x80000000u);
    return __uint_as_float(u);
}

// SA[l] = sum_{j=-6..6} A[clamp(l+j)] for chunk tc (13 elems)
__device__ __forceinline__ void build_sa(const float* A, float* SAb, int tc) {
    int l0 = tc * 13;
    if (l0 >= LROW) return;
    int l1 = min(l0 + 13, LROW);
    float sum = 0.f;
    #pragma unroll
    for (int j = -6; j <= 6; ++j) sum += A[clampi(l0 + j)];
    SAb[l0] = sum;
    for (int l = l0 + 1; l < l1; ++l) {
        sum += A[clampi(l + 6)] - A[clampi(l - 7)];
        SAb[l] = sum;
    }
}

__device__ __forceinline__ float ws_edge(int l, const float* lmed) {
    float w = 0.f;
    #pragma unroll
    for (int j = -6; j <= 6; ++j) {
        int idx = clampi(l + j);
        int ph = (idx < PERIOD) ? idx : idx - 2880;
        w += lmed[ph];
    }
    return w;
}

// ========== Kernel 1: medians + window-sum tables, 2 rows per block ========
__global__ __launch_bounds__(NT, 3) void stl_medians(const float* __restrict__ x,
                                                     float* __restrict__ ws) {
    __shared__ float    A[2][LROW];
    __shared__ float    SAb[2][LROW];
    __shared__ unsigned hist[32 * HISTW];   // hist[bin*49 + col], col = rr*24+p
    __shared__ unsigned rank_[48];
    __shared__ unsigned spre[48];
    __shared__ float    lmed[2][PERIOD];
    __shared__ float    Wtab[48];           // Wtab[col]

    const int d  = blockIdx.x;
    const int pp = (d & 7) * PCHUNK + (d >> 3);    // bijective XCD swizzle on pairs
    const int r0 = pp * 2;
    const int t  = threadIdx.x;
    const int b0 = r0 / NF,      f0 = r0 - b0 * NF;
    const int b1 = (r0 + 1) / NF, f1 = (r0 + 1) - b1 * NF;
    const size_t base0 = (size_t)b0 * (LROW * NF) + f0;
    const size_t base1 = (size_t)b1 * (LROW * NF) + f1;

    // load both rows; rr fastest -> adjacent lanes share 64B lines (same-b pairs)
    for (int i = t; i < 2 * LROW; i += NT) {
        int l = i >> 1, rr = i & 1;
        A[rr][l] = x[(rr ? base1 : base0) + (size_t)l * NF];
    }
    __syncthreads();

    for (int j = t; j < 448; j += NT) {
        int rr = (j >= 224) ? 1 : 0;
        build_sa(A[rr], SAb[rr], rr ? j - 224 : j);
    }
    // zero histogram once; scan re-zeroes each pass
    for (int i = t; i < 32 * HISTW; i += NT) hist[i] = 0;
    __syncthreads();

    const int col = t / 5;            // 0..51 (valid < 48)
    const int sub = t - col * 5;      // 0..4, owns cycles c = sub*25 + k
    const int rr  = col >> 4 >= 3 ? 1 : (col >= 24 ? 1 : 0);  // col/24
    const int p   = col - (col >= 24 ? 24 : 0);
    const bool act = (col < 48);

    for (int iter = 0; iter < 2; ++iter) {
        if (t < 48) rank_[t] = 60;            // reset rank (barrier below covers)

        unsigned kreg[25];
        if (act) {
            float wph = (iter == 1) ? Wtab[rr * 24 + (p + 18) % 24] : 0.f;
            #pragma unroll
            for (int k = 0; k < 25; ++k) {
                int c = sub * 25 + k;
                if (c < CYC) {
                    int l = c * PERIOD + p;
                    float w = wph;
                    if (iter == 1) {
                        if (c == 0 && p < 6)          w = ws_edge(l, lmed[rr]);
                        else if (c == 120 && p >= 18) w = ws_edge(l, lmed[rr]);
                    }
                    float tr = (SAb[rr][l] - w) * (1.f / 13.f);
                    kreg[k] = sortable(A[rr][l] - tr);
                }
            }
        }

        for (int pass = 0; pass < 4; ++pass) {
            if (act) {
                unsigned pref = (pass == 0) ? 0u : spre[col];
                int bsh = 27 - 5 * pass;
                #pragma unroll
                for (int k = 0; k < 25; ++k) {
                    int c = sub * 25 + k;
                    if (c < CYC) {
                        unsigned key = kreg[k];
                        bool match = (pass == 0) || ((key >> (bsh + 5)) == pref);
                        if (match)
                            atomicAdd(&hist[((key >> bsh) & 31u) * HISTW + col], 1u);
                    }
                }
            }
            __syncthreads();
            // parallel bin-scan: 32 lanes = 32 bins; 8 half-wave groups x 6 rounds
            {
                const int lane = t & 31;      // bin
                const int grp  = t >> 5;      // 0..7
                #pragma unroll
                for (int rnd = 0; rnd < 6; ++rnd) {
                    int cc = rnd * 8 + grp;
                    unsigned cnt = hist[lane * HISTW + cc];
                    unsigned cum = cnt;
                    #pragma unroll
                    for (int s = 1; s < 32; s <<= 1) {
                        unsigned v = __shfl_up(cum, s, 32);
                        if (lane >= s) cum += v;
                    }
                    unsigned r = rank_[cc];
                    if (cum > r && (cum - cnt) <= r) {   // unique hit lane
                        rank_[cc] = r - (cum - cnt);
                        spre[cc]  = (pass == 0) ? (unsigned)lane
                                                : ((spre[cc] << 5) | (unsigned)lane);
                    }
                    hist[lane * HISTW + cc] = 0;         // re-zero for next pass
                }
            }
            __syncthreads();
        }

        // reconstruct medians + window-sum table (lanes 0..47: single wave)
        if (t < 48) {
            int rr2 = (t >= 24) ? 1 : 0;
            int p2  = t - rr2 * 24;
            lmed[rr2][p2] = unsortable((spre[t] << 12) | 0x800u);
            float w = 0.f;
            #pragma unroll
            for (int j = 0; j < 13; ++j) {
                int ph = p2 + j; if (ph >= PERIOD) ph -= PERIOD;
                w += lmed[rr2][ph];
            }
            Wtab[t] = w;
        }
        __syncthreads();
    }

    if (t < 48) {
        int rr2 = (t >= 24) ? 1 : 0;
        int p2  = t - rr2 * 24;
        int bb  = rr2 ? b1 : b0;
        int ff  = rr2 ? f1 : f0;
        ws[((size_t)bb * 48 + p2) * NF + ff]      = lmed[rr2][p2];
        ws[((size_t)bb * 48 + 24 + p2) * NF + ff] = Wtab[t];
    }
}

// ================= Kernel 2: coalesced output generation ===================
__global__ __launch_bounds__(NT, 5) void stl_outputs(const float* __restrict__ x,
                                                     const float* __restrict__ ws,
                                                     float* __restrict__ out) {
    __shared__ float T[(LTILE + 12) * NF];   // rows l0-6 .. l0+29, f-major

    const int d   = blockIdx.x;
    const int blk = (d & 7) * K2CHUNK + (d >> 3);
    const int b  = blk / NLT;
    const int kk = blk - b * NLT;
    const int l0 = kk * LTILE;
    const int t  = threadIdx.x;
    const float* xb = x + (size_t)b * (LROW * NF);

    if (kk != 0 && kk != NLT - 1) {
        const float2* s2 = (const float2*)(xb + (size_t)(l0 - 6) * NF);
        float2* t2 = (float2*)T;
        for (int i = t; i < (LTILE + 12) * NF / 2; i += NT) t2[i] = s2[i];
    } else {
        for (int i = t; i < (LTILE + 12) * NF; i += NT) {
            int lr = i / NF;
            int ff = i - lr * NF;
            T[i] = xb[(size_t)clampi(l0 - 6 + lr) * NF + ff];
        }
    }
    __syncthreads();

    if (t < NF) {
        float lm[PERIOD], wt[PERIOD];
        const float* wrow = ws + (size_t)b * 48 * NF + t;
        #pragma unroll
        for (int i = 0; i < PERIOD; ++i) lm[i] = wrow[i * NF];
        #pragma unroll
        for (int i = 0; i < PERIOD; ++i) wt[i] = wrow[(PERIOD + i) * NF];

        float s13 = 0.f;
        #pragma unroll
        for (int r = 0; r < 13; ++r) s13 += T[r * NF + t];

        const bool edgeLo = (kk == 0), edgeHi = (kk == NLT - 1);
        const size_t S = (size_t)NROWS * LROW;
        const size_t obase = (size_t)b * (LROW * NF) + (size_t)l0 * NF + (size_t)t;

        #pragma unroll
        for (int j = 0; j < LTILE; ++j) {
            float W = wt[(j + 18) % 24];
            if (edgeLo && j < 6) {
                float w = 0.f;
                #pragma unroll
                for (int jj = -6; jj <= 6; ++jj) { int m = j + jj; if (m < 0) m = 0; w += lm[m]; }
                W = w;
            }
            if (edgeHi && j >= 18) {
                float w = 0.f;
                #pragma unroll
                for (int jj = -6; jj <= 6; ++jj) { int m = j + jj; if (m > 23) m = 23; w += lm[m]; }
                W = w;
            }
            float tr = (s13 - W) * (1.f / 13.f);
            float se = lm[j];
            float re = T[(j + 6) * NF + t] - tr - se;
            size_t o = obase + (size_t)(j * NF);
            out[o]         = tr;
            out[S + o]     = se;
            out[2 * S + o] = re;
            if (j < LTILE - 1)
                s13 += T[(j + 13) * NF + t] - T[j * NF + t];
        }
    }
}

extern "C" void kernel_launch(void* const* d_in, const int* in_sizes, int n_in,
                              void* d_out, int out_size, void* d_ws, size_t ws_size,
                              hipStream_t stream) {
    const float* x = (const float*)d_in[0];
    float* out = (float*)d_out;
    float* ws  = (float*)d_ws;     // NB*48*NF*4 = 2.55 MB
    (void)in_sizes; (void)n_in; (void)out_size; (void)ws_size;
    hipLaunchKernelGGL(stl_medians, dim3(NPAIR), dim3(NT), 0, stream, x, ws);
    hipLaunchKernelGGL(stl_outputs, dim3(K2GRID), dim3(NT), 0, stream, x, ws, out);
}

// Round 6
// 419.757 us; speedup vs baseline: 2.4657x; 2.4657x over previous
//
#include <hip/hip_runtime.h>

#define LROW    2904
#define PERIOD  24
#define CYC     121          // LROW / PERIOD (odd -> median = 0-indexed rank 60)
#define NT      256
#define NF      207
#define NB      64
#define NROWS   13248        // NB * NF
#define CHUNK   (NROWS / 8)
#define LTILE   24
#define NLT     (LROW / LTILE)   // 121
#define K2GRID  (NB * NLT)       // 7744 = 8 * 968
#define K2CHUNK (K2GRID / 8)
#define CSTR    133          // padded col stride: bank = (5p+c)%32 -> conflict-free

__device__ __forceinline__ int clampi(int i) {
    return i < 0 ? 0 : (i >= LROW ? LROW - 1 : i);
}
__device__ __forceinline__ unsigned sortable(float x) {
    unsigned u = __float_as_uint(x);
    return u ^ ((unsigned)((int)u >> 31) | 0x80000000u);
}
__device__ __forceinline__ float unsortable(unsigned k) {
    unsigned u = ((int)k >= 0) ? ~k : (k ^ 0x80000000u);
    return __uint_as_float(u);
}

// sum_{j=-6..6} lmed[phase(clamp(l+j))] for edge l (l<6 or l>=LROW-6)
__device__ __forceinline__ float ws_edge(int l, const float* lmed) {
    float w = 0.f;
    #pragma unroll
    for (int j = -6; j <= 6; ++j) {
        int idx = clampi(l + j);
        int ph = (idx < PERIOD) ? idx : idx - 2880;
        w += lmed[ph];
    }
    return w;
}

// ballot radix select of rank 60 among 121 keys (2/lane; dead k1 lanes hold 0,
// which never matches an odd `want`). Returns top-20-bit prefix of the key.
// `act` is shfl-poisoned into a VGPR so bookkeeping stays on VALU (the scalar
// pipe is 1/CU and would bottleneck at ~11 SALU/bit otherwise).
__device__ __forceinline__ unsigned sel60(unsigned k0, unsigned k1) {
    int act = __shfl(121, 0);
    int r = 60;
    unsigned pref = 0;
    #pragma unroll
    for (int bit = 31; bit >= 12; --bit) {
        unsigned pw   = pref << 1;
        unsigned want = pw | 1u;
        unsigned long long m0 = __ballot((k0 >> bit) == want);
        unsigned long long m1 = __ballot((k1 >> bit) == want);
        int ones  = __popcll(m0) + __popcll(m1);
        int zeros = act - ones;
        bool take1 = (r >= zeros);
        pref = take1 ? want : pw;
        r    = take1 ? r - zeros : r;
        act  = take1 ? ones : zeros;
    }
    return pref;
}

// ========== Kernel 1: medians + window-sum table (ballot select) ===========
__global__ __launch_bounds__(NT, 6) void stl_medians(const float* __restrict__ x,
                                                     float* __restrict__ ws) {
    __shared__ float At[PERIOD][CSTR];    // phase-major input
    __shared__ float SAt[PERIOD][CSTR];   // phase-major window-13 clamped sum
    __shared__ float lmedA[PERIOD];       // iter-0 medians
    __shared__ float lmedB[PERIOD];       // iter-1 medians
    __shared__ float Wtab[PERIOD];        // Wtab[q] = sum_{j=0..12} lmed[(q+j)%24]

    const int d   = blockIdx.x;
    const int row = (d & 7) * CHUNK + (d >> 3);    // bijective XCD swizzle
    const int b = row / NF;
    const int f = row - b * NF;
    const int t = threadIdx.x;
    const size_t rowbase = (size_t)b * (LROW * NF) + (size_t)f;

    // ---- load (strided global, L2/L3-absorbed) -> transposed LDS
    for (int l = t; l < LROW; l += NT)
        At[l % PERIOD][l / PERIOD] = x[rowbase + (size_t)l * NF];
    __syncthreads();

    // ---- SAt: lane = cycle c, slide over p (l = 24c + p is sequential in p)
    if (t < CYC) {
        const int c = t;
        float s = 0.f;
        #pragma unroll
        for (int j = -6; j <= 6; ++j) {
            int l = clampi(c * PERIOD + j);
            s += At[l % PERIOD][l / PERIOD];
        }
        SAt[0][c] = s;
        #pragma unroll 1
        for (int p = 1; p < PERIOD; ++p) {
            int la = clampi(c * PERIOD + p + 6);
            int lr = clampi(c * PERIOD + p - 7);
            s += At[la % PERIOD][la / PERIOD] - At[lr % PERIOD][lr / PERIOD];
            SAt[p][c] = s;
        }
    }
    __syncthreads();

    const int wid  = t >> 6;
    const int lane = t & 63;
    const int c1   = 64 + lane;

    // ================= iter 0: trend = SA/13, select all 24 phases ========
    #pragma unroll 1
    for (int j = 0; j < 6; ++j) {
        const int p = wid * 6 + j;
        float tr0 = SAt[p][lane] * (1.f / 13.f);
        unsigned k0 = sortable(At[p][lane] - tr0);
        unsigned k1 = 0u;
        if (c1 < CYC) {
            float tr1 = SAt[p][c1] * (1.f / 13.f);
            k1 = sortable(At[p][c1] - tr1);
        }
        unsigned pref = sel60(k0, k1);
        if (lane == 0) lmedA[p] = unsortable((pref << 12) | 0x800u);
    }
    __syncthreads();
    if (t < PERIOD) {                       // Wtab0 from lmedA
        float w = 0.f;
        #pragma unroll
        for (int j2 = 0; j2 < 13; ++j2) {
            int ph = t + j2; if (ph >= PERIOD) ph -= PERIOD;
            w += lmedA[ph];
        }
        Wtab[t] = w;
    }
    __syncthreads();

    // ================= iter 1 =============================================
    // Interior phases (6..17) have no edge element: keys shift by a phase-
    // constant -> median translates exactly; only 12 edge phases re-select.
    #pragma unroll 1
    for (int j = 0; j < 3; ++j) {
        const int e = wid * 3 + j;          // 0..11
        const int p = (e < 6) ? e : e + 12; // {0..5, 18..23}
        float wph = Wtab[(p + 18) % 24];
        float w0 = wph, w1 = wph;
        if (p < 6)  { if (lane == 0)  w0 = ws_edge(p, lmedA); }
        else        { if (lane == 56) w1 = ws_edge(2880 + p, lmedA); }
        float tr0 = (SAt[p][lane] - w0) * (1.f / 13.f);
        unsigned k0 = sortable(At[p][lane] - tr0);
        unsigned k1 = 0u;
        if (c1 < CYC) {
            float tr1 = (SAt[p][c1] - w1) * (1.f / 13.f);
            k1 = sortable(At[p][c1] - tr1);
        }
        unsigned pref = sel60(k0, k1);
        if (lane == 0) lmedB[p] = unsortable((pref << 12) | 0x800u);
    }
    __syncthreads();
    if (t < PERIOD) {
        // interior translate (writes by lanes 6..17 precede reads below in
        // wave program order -> no barrier needed within the wave)
        if (t >= 6 && t < 18)
            lmedB[t] = lmedA[t] + Wtab[(t + 18) % 24] * (1.f / 13.f);
        float w = 0.f;
        #pragma unroll
        for (int j2 = 0; j2 < 13; ++j2) {
            int ph = t + j2; if (ph >= PERIOD) ph -= PERIOD;
            w += lmedB[ph];
        }
        Wtab[t] = w;                        // Wtab1 (after all reads of Wtab0)
    }
    __syncthreads();

    // ws layout [b][48][f]: i<24 -> lmedB, i>=24 -> Wtab1
    if (t < 48) {
        int isW = t >= 24;
        int p2  = t - (isW ? 24 : 0);
        ws[((size_t)b * 48 + t) * NF + f] = isW ? Wtab[p2] : lmedB[p2];
    }
}

// ================= Kernel 2: coalesced output generation (R4, unchanged) ===
__global__ __launch_bounds__(NT, 5) void stl_outputs(const float* __restrict__ x,
                                                     const float* __restrict__ ws,
                                                     float* __restrict__ out) {
    __shared__ float T[(LTILE + 12) * NF];   // rows l0-6 .. l0+29, f-major

    const int d   = blockIdx.x;
    const int blk = (d & 7) * K2CHUNK + (d >> 3);
    const int b  = blk / NLT;
    const int kk = blk - b * NLT;
    const int l0 = kk * LTILE;
    const int t  = threadIdx.x;
    const float* xb = x + (size_t)b * (LROW * NF);

    if (kk != 0 && kk != NLT - 1) {
        const float2* s2 = (const float2*)(xb + (size_t)(l0 - 6) * NF);
        float2* t2 = (float2*)T;
        for (int i = t; i < (LTILE + 12) * NF / 2; i += NT) t2[i] = s2[i];
    } else {
        for (int i = t; i < (LTILE + 12) * NF; i += NT) {
            int lr = i / NF;
            int ff = i - lr * NF;
            T[i] = xb[(size_t)clampi(l0 - 6 + lr) * NF + ff];
        }
    }
    __syncthreads();

    if (t < NF) {
        float lm[PERIOD], wt[PERIOD];
        const float* wrow = ws + (size_t)b * 48 * NF + t;
        #pragma unroll
        for (int i = 0; i < PERIOD; ++i) lm[i] = wrow[i * NF];
        #pragma unroll
        for (int i = 0; i < PERIOD; ++i) wt[i] = wrow[(PERIOD + i) * NF];

        float s13 = 0.f;
        #pragma unroll
        for (int r = 0; r < 13; ++r) s13 += T[r * NF + t];

        const bool edgeLo = (kk == 0), edgeHi = (kk == NLT - 1);
        const size_t S = (size_t)NROWS * LROW;
        const size_t obase = (size_t)b * (LROW * NF) + (size_t)l0 * NF + (size_t)t;

        #pragma unroll
        for (int j = 0; j < LTILE; ++j) {
            float W = wt[(j + 18) % 24];
            if (edgeLo && j < 6) {
                float w = 0.f;
                #pragma unroll
                for (int jj = -6; jj <= 6; ++jj) { int m = j + jj; if (m < 0) m = 0; w += lm[m]; }
                W = w;
            }
            if (edgeHi && j >= 18) {
                float w = 0.f;
                #pragma unroll
                for (int jj = -6; jj <= 6; ++jj) { int m = j + jj; if (m > 23) m = 23; w += lm[m]; }
                W = w;
            }
            float tr = (s13 - W) * (1.f / 13.f);
            float se = lm[j];
            float re = T[(j + 6) * NF + t] - tr - se;
            size_t o = obase + (size_t)(j * NF);
            out[o]         = tr;
            out[S + o]     = se;
            out[2 * S + o] = re;
            if (j < LTILE - 1)
                s13 += T[(j + 13) * NF + t] - T[j * NF + t];
        }
    }
}

extern "C" void kernel_launch(void* const* d_in, const int* in_sizes, int n_in,
                              void* d_out, int out_size, void* d_ws, size_t ws_size,
                              hipStream_t stream) {
    const float* x = (const float*)d_in[0];
    float* out = (float*)d_out;
    float* ws  = (float*)d_ws;     // NB*48*NF*4 = 2.55 MB
    (void)in_sizes; (void)n_in; (void)out_size; (void)ws_size;
    hipLaunchKernelGGL(stl_medians, dim3(NROWS), dim3(NT), 0, stream, x, ws);
    hipLaunchKernelGGL(stl_outputs, dim3(K2GRID), dim3(NT), 0, stream, x, ws, out);
}

// Round 7
// 378.690 us; speedup vs baseline: 2.7331x; 1.1084x over previous
//
#include <hip/hip_runtime.h>

#define LROW    2904
#define PERIOD  24
#define CYC     121          // LROW / PERIOD (odd -> median = 0-indexed rank 60)
#define NT      256
#define NF      207
#define NB      64
#define NROWS   13248        // NB * NF
#define CHUNK   (NROWS / 8)
#define LTILE   24
#define NLT     (LROW / LTILE)   // 121
#define K2GRID  (NB * NLT)       // 7744 = 8 * 968
#define K2CHUNK (K2GRID / 8)
#define CSTR    133          // padded col stride: bank = (5p+c)%32 -> conflict-free

__device__ __forceinline__ int clampi(int i) {
    return i < 0 ? 0 : (i >= LROW ? LROW - 1 : i);
}

// 16-bit absolute fixed-point key: grid 2^-12, range [-8, 8). Monotone.
__device__ __forceinline__ unsigned quantk(float d) {
    int ki = (int)fmaf(d, 4096.f, 32768.f);   // trunc toward 0; monotone after clamp
    ki = ki < 0 ? 0 : (ki > 65535 ? 65535 : ki);
    return (unsigned)ki;
}
__device__ __forceinline__ float reconk(unsigned pref) {
    return ((float)(int)pref - 32767.5f) * (1.f / 4096.f);   // bucket midpoint
}

// sum_{j=-6..6} lmed[phase(clamp(l+j))] for edge l (l<6 or l>=LROW-6)
__device__ __forceinline__ float ws_edge(int l, const float* lmed) {
    float w = 0.f;
    #pragma unroll
    for (int j = -6; j <= 6; ++j) {
        int idx = clampi(l + j);
        int ph = (idx < PERIOD) ? idx : idx - 2880;
        w += lmed[ph];
    }
    return w;
}

// Two interleaved ballot radix selects of rank 60 among 121 16-bit keys
// (2 keys/lane; dead k1 lanes hold 0xFFFFFFFF -> never match a valid prefix).
// Interleaving fills the per-bit serial-chain latency with the sibling chain.
// act/r/pref bookkeeping poisoned into VGPRs (shfl) so chains don't serialize
// through the single SCC flag / scalar pipe.
__device__ __forceinline__ void sel60x2(unsigned a0, unsigned a1,
                                        unsigned b0, unsigned b1,
                                        unsigned& prefA, unsigned& prefB) {
    int actA = __shfl(121, 0);
    int actB = actA;
    int rA = 60, rB = 60;
    unsigned pA = 0, pB = 0;
    #pragma unroll
    for (int bit = 15; bit >= 0; --bit) {
        unsigned wA = (pA << 1) | 1u;
        unsigned wB = (pB << 1) | 1u;
        unsigned long long mA0 = __ballot((a0 >> bit) == wA);
        unsigned long long mA1 = __ballot((a1 >> bit) == wA);
        unsigned long long mB0 = __ballot((b0 >> bit) == wB);
        unsigned long long mB1 = __ballot((b1 >> bit) == wB);
        int onesA = __popcll(mA0) + __popcll(mA1);
        int onesB = __popcll(mB0) + __popcll(mB1);
        int zA = actA - onesA, zB = actB - onesB;
        bool tA = (rA >= zA), tB = (rB >= zB);
        pA = tA ? wA : wA - 1u;  pB = tB ? wB : wB - 1u;
        rA = tA ? rA - zA : rA;  rB = tB ? rB - zB : rB;
        actA = tA ? onesA : zA;  actB = tB ? onesB : zB;
    }
    prefA = pA; prefB = pB;
}

// ========== Kernel 1: medians + window-sum table ===========================
__global__ __launch_bounds__(NT, 6) void stl_medians(const float* __restrict__ x,
                                                     float* __restrict__ ws) {
    __shared__ float At[PERIOD][CSTR];    // phase-major input
    __shared__ float SAt[PERIOD][CSTR];   // phase-major window-13 clamped sum
    __shared__ float lmedA[PERIOD];
    __shared__ float lmedB[PERIOD];
    __shared__ float Wtab[PERIOD];

    const int d   = blockIdx.x;
    const int row = (d & 7) * CHUNK + (d >> 3);    // bijective XCD swizzle
    const int b = row / NF;
    const int f = row - b * NF;
    const int t = threadIdx.x;
    const size_t rowbase = (size_t)b * (LROW * NF) + (size_t)f;

    // ---- load (strided; L2/L3-absorbed) -> transposed LDS, incremental (p,c)
    {
        int l = t, c = t / PERIOD, p = t - c * PERIOD;
        while (l < LROW) {
            At[p][c] = x[rowbase + (size_t)l * NF];
            l += NT; p += 16; c += 10;
            if (p >= PERIOD) { p -= PERIOD; ++c; }
        }
    }
    __syncthreads();

    // ---- SAt: 242 threads, 2 half-period sliding segments per cycle column
    if (t < 242) {
        const int h  = (t >= 121) ? 1 : 0;
        const int c  = t - 121 * h;
        const int pb = 12 * h;
        const int l0 = c * PERIOD + pb;
        float s = 0.f;
        #pragma unroll
        for (int j = -6; j <= 6; ++j) {
            int lm = clampi(l0 + j);
            s += At[lm % PERIOD][lm / PERIOD];
        }
        SAt[pb][c] = s;
        #pragma unroll
        for (int q = 1; q < 12; ++q) {
            int la = clampi(l0 + q + 6), lr = clampi(l0 + q - 7);
            s += At[la % PERIOD][la / PERIOD] - At[lr % PERIOD][lr / PERIOD];
            SAt[pb + q][c] = s;
        }
    }
    __syncthreads();

    const int wid  = t >> 6;
    const int lane = t & 63;
    const int c1   = 64 + lane;
    const bool has1 = (c1 < CYC);

    // ================= iter 0: trend = SA/13; 3 select-pairs per wave ======
    #pragma unroll
    for (int pr = 0; pr < 3; ++pr) {
        const int pA = wid * 6 + pr * 2, pB = pA + 1;
        unsigned a0 = quantk(At[pA][lane] - SAt[pA][lane] * (1.f / 13.f));
        unsigned b0 = quantk(At[pB][lane] - SAt[pB][lane] * (1.f / 13.f));
        unsigned a1 = 0xFFFFFFFFu, b1 = 0xFFFFFFFFu;
        if (has1) {
            a1 = quantk(At[pA][c1] - SAt[pA][c1] * (1.f / 13.f));
            b1 = quantk(At[pB][c1] - SAt[pB][c1] * (1.f / 13.f));
        }
        unsigned prA, prB;
        sel60x2(a0, a1, b0, b1, prA, prB);
        if (lane == 0) { lmedA[pA] = reconk(prA); lmedA[pB] = reconk(prB); }
    }
    __syncthreads();
    if (t < PERIOD) {                       // Wtab0
        float w = 0.f;
        #pragma unroll
        for (int j = 0; j < 13; ++j) {
            int ph = t + j; if (ph >= PERIOD) ph -= PERIOD;
            w += lmedA[ph];
        }
        Wtab[t] = w;
    }
    __syncthreads();

    // ================= iter 1: only 12 edge phases re-select ===============
    // pairs (j, 18+j), j=0..5; wave w: j=w, plus j=4+w for w<2
    #pragma unroll 1
    for (int rep = 0; rep < 2; ++rep) {
        const int j = (rep == 0) ? wid : (wid < 2 ? 4 + wid : 99);
        if (j > 5) continue;
        const int pA = j, pB = 18 + j;
        const float wA = Wtab[j + 18];      // (pA+18)%24
        const float wB = Wtab[j + 12];      // (pB+18)%24
        float wA0 = (lane == 0) ? ws_edge(pA, lmedA) : wA;   // c=0 edge elem
        unsigned a0 = quantk(At[pA][lane] - (SAt[pA][lane] - wA0) * (1.f / 13.f));
        unsigned b0 = quantk(At[pB][lane] - (SAt[pB][lane] - wB)  * (1.f / 13.f));
        unsigned a1 = 0xFFFFFFFFu, b1 = 0xFFFFFFFFu;
        if (has1) {
            float wB1 = (lane == 56) ? ws_edge(2880 + pB, lmedA) : wB;  // c=120
            a1 = quantk(At[pA][c1] - (SAt[pA][c1] - wA)  * (1.f / 13.f));
            b1 = quantk(At[pB][c1] - (SAt[pB][c1] - wB1) * (1.f / 13.f));
        }
        unsigned prA, prB;
        sel60x2(a0, a1, b0, b1, prA, prB);
        if (lane == 0) { lmedB[pA] = reconk(prA); lmedB[pB] = reconk(prB); }
    }
    __syncthreads();
    if (t < PERIOD) {
        // interior phases translate exactly: median(d + W/13) = m0 + W/13
        if (t >= 6 && t < 18)
            lmedB[t] = lmedA[t] + Wtab[t - 6] * (1.f / 13.f);
        float w = 0.f;
        #pragma unroll
        for (int j2 = 0; j2 < 13; ++j2) {
            int ph = t + j2; if (ph >= PERIOD) ph -= PERIOD;
            w += lmedB[ph];
        }
        Wtab[t] = w;                        // Wtab1 (reads precede write, in-wave)
    }
    __syncthreads();

    if (t < 48) {
        int isW = (t >= 24);
        int p2  = t - (isW ? 24 : 0);
        ws[((size_t)b * 48 + t) * NF + f] = isW ? Wtab[p2] : lmedB[p2];
    }
}

// ================= Kernel 2: coalesced outputs (+ nontemporal stores) ======
__global__ __launch_bounds__(NT, 5) void stl_outputs(const float* __restrict__ x,
                                                     const float* __restrict__ ws,
                                                     float* __restrict__ out) {
    __shared__ float T[(LTILE + 12) * NF];   // rows l0-6 .. l0+29, f-major

    const int d   = blockIdx.x;
    const int blk = (d & 7) * K2CHUNK + (d >> 3);
    const int b  = blk / NLT;
    const int kk = blk - b * NLT;
    const int l0 = kk * LTILE;
    const int t  = threadIdx.x;
    const float* xb = x + (size_t)b * (LROW * NF);

    if (kk != 0 && kk != NLT - 1) {
        const float2* s2 = (const float2*)(xb + (size_t)(l0 - 6) * NF);
        float2* t2 = (float2*)T;
        for (int i = t; i < (LTILE + 12) * NF / 2; i += NT) t2[i] = s2[i];
    } else {
        for (int i = t; i < (LTILE + 12) * NF; i += NT) {
            int lr = i / NF;
            int ff = i - lr * NF;
            T[i] = xb[(size_t)clampi(l0 - 6 + lr) * NF + ff];
        }
    }
    __syncthreads();

    if (t < NF) {
        float lm[PERIOD], wt[PERIOD];
        const float* wrow = ws + (size_t)b * 48 * NF + t;
        #pragma unroll
        for (int i = 0; i < PERIOD; ++i) lm[i] = wrow[i * NF];
        #pragma unroll
        for (int i = 0; i < PERIOD; ++i) wt[i] = wrow[(PERIOD + i) * NF];

        float s13 = 0.f;
        #pragma unroll
        for (int r = 0; r < 13; ++r) s13 += T[r * NF + t];

        const bool edgeLo = (kk == 0), edgeHi = (kk == NLT - 1);
        const size_t S = (size_t)NROWS * LROW;
        const size_t obase = (size_t)b * (LROW * NF) + (size_t)l0 * NF + (size_t)t;

        #pragma unroll
        for (int j = 0; j < LTILE; ++j) {
            float W = wt[(j + 18) % 24];
            if (edgeLo && j < 6) {
                float w = 0.f;
                #pragma unroll
                for (int jj = -6; jj <= 6; ++jj) { int m = j + jj; if (m < 0) m = 0; w += lm[m]; }
                W = w;
            }
            if (edgeHi && j >= 18) {
                float w = 0.f;
                #pragma unroll
                for (int jj = -6; jj <= 6; ++jj) { int m = j + jj; if (m > 23) m = 23; w += lm[m]; }
                W = w;
            }
            float tr = (s13 - W) * (1.f / 13.f);
            float se = lm[j];
            float re = T[(j + 6) * NF + t] - tr - se;
            size_t o = obase + (size_t)(j * NF);
            __builtin_nontemporal_store(tr, &out[o]);
            __builtin_nontemporal_store(se, &out[S + o]);
            __builtin_nontemporal_store(re, &out[2 * S + o]);
            if (j < LTILE - 1)
                s13 += T[(j + 13) * NF + t] - T[j * NF + t];
        }
    }
}

extern "C" void kernel_launch(void* const* d_in, const int* in_sizes, int n_in,
                              void* d_out, int out_size, void* d_ws, size_t ws_size,
                              hipStream_t stream) {
    const float* x = (const float*)d_in[0];
    float* out = (float*)d_out;
    float* ws  = (float*)d_ws;     // NB*48*NF*4 = 2.55 MB
    (void)in_sizes; (void)n_in; (void)out_size; (void)ws_size;
    hipLaunchKernelGGL(stl_medians, dim3(NROWS), dim3(NT), 0, stream, x, ws);
    hipLaunchKernelGGL(stl_outputs, dim3(K2GRID), dim3(NT), 0, stream, x, ws, out);
}